// Round 6
// baseline (91.467 us; speedup 1.0000x reference)
//
#include <hip/hip_runtime.h>
#include <hip/hip_bf16.h>
#include <cstdint>

// CTC forward loss (keras ctc_batch_cost), B=64 T=1024 L=128 V=512.
// Two-phase:
//   K1 (gather, 4096 blocks, all CUs): y_pred rows -> LDS -> gather the 129
//      needed probs per (b,t), bf16-pack -> compact[B][T][68 u32] in d_ws.
//      Waves fully independent (stage+gather own rows), no barriers.
//   K2 (scan, 64 blocks): probability-domain scaled forward algorithm.
//      Consumer wave: lane j owns states 4j..4j+3; per step ONE conflict-free
//      ds_read_b32 (packed bf16 pair labA,labB) + broadcast blank read.
//      Producer wave: 5 global_load_lds/chunk, 6 chunks ahead, counted vmcnt.
//      DPP for all cross-lane; renorm every 4 steps (exact pow2), deferred.
// Fallback to single-kernel r5 design if ws_size too small.

#define CTC_B 64
#define CTC_T 1024
#define CTC_L 128
#define CTC_V 512
#define BLANK (CTC_V - 1)
#define EPSF 1e-7f
#define LN2F 0.69314718055994530942f

#define ROWW 68               // u32 per compact row: 64 pairs + blank + 3 pad
#define K1ROWS 16             // time rows per K1 block
#define CHUNK 16
#define NBUF  8
#define NCH   (CTC_T / CHUNK) // 64
#define BIASE 60

__device__ __forceinline__ void gld_lds16(const uint32_t* g, uint32_t* l) {
    __builtin_amdgcn_global_load_lds(
        (const __attribute__((address_space(1))) unsigned int*)g,
        (__attribute__((address_space(3))) unsigned int*)l, 16, 0, 0);
}
__device__ __forceinline__ void gld_lds4(const uint32_t* g, uint32_t* l) {
    __builtin_amdgcn_global_load_lds(
        (const __attribute__((address_space(1))) unsigned int*)g,
        (__attribute__((address_space(3))) unsigned int*)l, 4, 0, 0);
}
__device__ __forceinline__ void gld_lds16f(const float* g, float* l) {
    __builtin_amdgcn_global_load_lds(
        (const __attribute__((address_space(1))) unsigned int*)g,
        (__attribute__((address_space(3))) unsigned int*)l, 16, 0, 0);
}

template<int CTRL>
__device__ __forceinline__ float dpp_mov0(float v) {
    int r = __builtin_amdgcn_update_dpp(0, __float_as_int(v), CTRL, 0xf, 0xf, false);
    return __int_as_float(r);
}
template<int CTRL>
__device__ __forceinline__ float dpp_max(float v) {
    int r = __builtin_amdgcn_update_dpp(__float_as_int(v), __float_as_int(v),
                                        CTRL, 0xf, 0xf, false);
    return fmaxf(v, __int_as_float(r));
}

__device__ __forceinline__ uint32_t rne16(float x) {
    return (__float_as_uint(x) + 0x8000u) >> 16;   // bf16 round-to-nearest-ish
}

// ---------------- K1: gather + bf16 compact ----------------
__global__ __launch_bounds__(256, 1)
void ctc_gather(const int* __restrict__ y_true,
                const float* __restrict__ y_pred,
                uint32_t* __restrict__ cmp) {
    __shared__ __align__(16) float rows[K1ROWS][CTC_V];   // 32 KB

    const int bid = blockIdx.x;
    const int b = bid >> 6;               // batch row
    const int t0 = (bid & 63) * K1ROWS;   // time tile
    const int w = threadIdx.x >> 6;       // wave 0..3 (independent)
    const int lane = threadIdx.x & 63;
    const float* __restrict__ yb = y_pred + ((size_t)b * CTC_T + t0) * CTC_V;

    // labels for this lane's two slots
    const int2 lp = *(const int2*)&y_true[b * CTC_L + 2 * lane];

    // stage rows 4w..4w+3 (this wave's own rows), coalesced 16B/lane
#pragma unroll
    for (int r = 0; r < 4; ++r) {
        const int row = 4 * w + r;
        const float* g = yb + (size_t)row * CTC_V + lane * 4;
        gld_lds16f(g, &rows[row][0]);
        gld_lds16f(g + 256, &rows[row][256]);
    }
    asm volatile("s_waitcnt vmcnt(0)" ::: "memory");

    // gather + pack + store (wave-local rows; no barrier needed)
#pragma unroll
    for (int r = 0; r < 4; ++r) {
        const int row = 4 * w + r;
        const float* rowp = &rows[row][0];
        const float c0 = rowp[lp.x];
        const float c1 = rowp[lp.y];
        const uint32_t pk = rne16(c0) | (rne16(c1) << 16);
        uint32_t* od = cmp + ((size_t)b * CTC_T + t0 + row) * ROWW;
        od[lane] = pk;
        if (lane == 63) od[64] = rne16(rowp[BLANK]);
    }
}

// ---------------- K2: scan over compact bf16 ----------------
__global__ __launch_bounds__(128, 1)
void ctc_scan(const int* __restrict__ y_true,
              const uint32_t* __restrict__ cmp,
              float* __restrict__ out) {
    __shared__ __align__(16) uint32_t ring[NBUF][CHUNK][ROWW];  // 34.8 KB

    const int b = blockIdx.x;
    const int wave = threadIdx.x >> 6;
    const int lane = threadIdx.x & 63;
    const uint32_t* __restrict__ cb = cmp + (size_t)b * CTC_T * ROWW;

    if (wave == 1) {
        // ----------------- producer -----------------
#define ISSUE(c_) do {                                                     \
            const uint32_t* g_ = cb + (size_t)(c_) * (CHUNK * ROWW);       \
            uint32_t* d_ = &ring[(c_) & (NBUF - 1)][0][0];                 \
            gld_lds16(g_ + lane * 4,        d_);                           \
            gld_lds16(g_ + 256 + lane * 4,  d_ + 256);                     \
            gld_lds16(g_ + 512 + lane * 4,  d_ + 512);                     \
            gld_lds16(g_ + 768 + lane * 4,  d_ + 768);                     \
            gld_lds4 (g_ + 1024 + lane,     d_ + 1024);                    \
        } while (0)
        ISSUE(0); ISSUE(1); ISSUE(2); ISSUE(3); ISSUE(4); ISSUE(5);
        asm volatile("s_waitcnt vmcnt(25)" ::: "memory");
        __builtin_amdgcn_s_barrier();
        __builtin_amdgcn_sched_barrier(0);
        for (int c = 0; c < NCH; ++c) {
            if (c + 6 < NCH) ISSUE(c + 6);
            const int K = (NCH - 1 - c < 6) ? (NCH - 1 - c) : 6;
            if (K == 6)      asm volatile("s_waitcnt vmcnt(25)" ::: "memory");
            else if (K == 5) asm volatile("s_waitcnt vmcnt(20)" ::: "memory");
            else if (K == 4) asm volatile("s_waitcnt vmcnt(15)" ::: "memory");
            else if (K == 3) asm volatile("s_waitcnt vmcnt(10)" ::: "memory");
            else if (K == 2) asm volatile("s_waitcnt vmcnt(5)"  ::: "memory");
            else if (K == 1) asm volatile("s_waitcnt vmcnt(0)"  ::: "memory");
            __builtin_amdgcn_s_barrier();
            __builtin_amdgcn_sched_barrier(0);
        }
        return;
#undef ISSUE
    }

    // ----------------- consumer -----------------
    const int labA = y_true[b * CTC_L + 2 * lane];
    const int labB = y_true[b * CTC_L + 2 * lane + 1];
    const int labPrev = __shfl_up(labB, 1);
    const float msk1 = (labA != labPrev) ? 1.0f : 0.0f;
    const float msk3 = (labB != labA) ? 1.0f : 0.0f;

    float a0 = 0.0f, a1 = 0.0f, a2 = 0.0f, a3 = 0.0f, a4 = 0.0f;
    float curScale = 1.0f;
    int curE = 0, Eacc = 0;

    uint32_t vA0, vA1, vA2, vA3, bA0, bA1, bA2, bA3;
    uint32_t vB0, vB1, vB2, vB3, bB0, bB1, bB2, bB3;
    uint32_t vC0, vC1, vC2, vC3, bC0, bC1, bC2, bC3;

#define LOADG(S, l_) do {                                                  \
        const uint32_t* r0_ = bufc + ((l_) + 0) * ROWW;                    \
        const uint32_t* r1_ = bufc + ((l_) + 1) * ROWW;                    \
        const uint32_t* r2_ = bufc + ((l_) + 2) * ROWW;                    \
        const uint32_t* r3_ = bufc + ((l_) + 3) * ROWW;                    \
        v##S##0 = r0_[lane]; b##S##0 = r0_[64];                            \
        v##S##1 = r1_[lane]; b##S##1 = r1_[64];                            \
        v##S##2 = r2_[lane]; b##S##2 = r2_[64];                            \
        v##S##3 = r3_[lane]; b##S##3 = r3_[64];                            \
    } while (0)

#define DOSTEP(S, k) do {                                                  \
        const float pb_ = __uint_as_float(b##S##k << 16) + EPSF;           \
        const float pA_ = __uint_as_float(v##S##k << 16) + EPSF;           \
        const float pB_ = __uint_as_float(v##S##k & 0xffff0000u) + EPSF;   \
        const float pm1_ = dpp_mov0<0x138>(a3); /* wave_shr:1, lane0->0 */ \
        const float n0_ = (a0 + pm1_) * pb_;                               \
        const float n1_ = fmaf(msk1, pm1_, a0 + a1) * pA_;                 \
        const float n2_ = (a1 + a2) * pb_;                                 \
        const float n3_ = fmaf(msk3, a1, a2 + a3) * pB_;                   \
        const float n4_ = (a3 + a4) * pb_;                                 \
        a0 = n0_; a1 = n1_; a2 = n2_; a3 = n3_; a4 = n4_;                  \
    } while (0)

#define DORN() do {                                                        \
        a0 *= curScale; a1 *= curScale; a2 *= curScale;                    \
        a3 *= curScale; a4 *= curScale;                                    \
        Eacc += curE;                                                      \
        float m_ = fmaxf(fmaxf(fmaxf(a0, a1), fmaxf(a2, a3)), a4);         \
        m_ = dpp_max<0x111>(m_);  /* row_shr:1  */                         \
        m_ = dpp_max<0x112>(m_);  /* row_shr:2  */                         \
        m_ = dpp_max<0x114>(m_);  /* row_shr:4  */                         \
        m_ = dpp_max<0x118>(m_);  /* row_shr:8  */                         \
        m_ = dpp_max<0x142>(m_);  /* row_bcast:15 */                       \
        m_ = dpp_max<0x143>(m_);  /* row_bcast:31 */                       \
        const int mb_ = __builtin_amdgcn_readlane(__float_as_int(m_), 63); \
        const int e_ = (mb_ >> 23) & 255;                                  \
        int k_ = 127 + BIASE + 127 - e_;                                   \
        k_ = k_ > 254 ? 254 : (k_ < 1 ? 1 : k_);                           \
        curScale = __int_as_float((unsigned)k_ << 23);                     \
        curE = 127 - k_;                                                   \
    } while (0)

#define PROC4_RN(S) do {                                                   \
        DOSTEP(S, 0); DORN();                                              \
        DOSTEP(S, 1); DOSTEP(S, 2); DOSTEP(S, 3);                          \
    } while (0)

    __builtin_amdgcn_s_barrier();   // chunk 0 ready
    __builtin_amdgcn_sched_barrier(0);

    for (int c = 0; c < NCH; ++c) {
        const uint32_t* bufc = &ring[c & (NBUF - 1)][0][0];
        if (c == 0) {
            const uint32_t u0 = bufc[0];    // broadcast: slot pair 0 of t=0
            const uint32_t ub0 = bufc[64];  // blank of t=0
            LOADG(A, 0); LOADG(B, 4); LOADG(C, 8);
            const float pb0 = __uint_as_float(ub0 << 16) + EPSF;
            const float pl0 = __uint_as_float(u0 << 16) + EPSF;
            a0 = (lane == 0) ? pb0 : 0.0f;
            a1 = (lane == 0) ? pl0 : 0.0f;
            DOSTEP(A, 1); DOSTEP(A, 2); DOSTEP(A, 3);   // t = 1..3
            LOADG(A, 12);
            PROC4_RN(B);                                // t = 4..7  (renorm @4)
            PROC4_RN(C);                                // t = 8..11
            PROC4_RN(A);                                // t = 12..15
        } else {
            LOADG(A, 0); LOADG(B, 4); LOADG(C, 8);
            PROC4_RN(A); LOADG(A, 12);
            PROC4_RN(B); PROC4_RN(C); PROC4_RN(A);
        }
        __builtin_amdgcn_s_barrier();
        __builtin_amdgcn_sched_barrier(0);
    }

    if (lane == 63) {
        out[b] = -(logf(a3 + a4) + (float)Eacc * LN2F);
    }
#undef PROC4_RN
#undef DORN
#undef DOSTEP
#undef LOADG
}

// ---------------- fallback: round-5 single kernel ----------------
#define F_CHUNK 16
#define F_NBUF  4
#define F_NCH   (CTC_T / F_CHUNK)

__global__ __launch_bounds__(256, 1)
void ctc_fwd_stream(const int* __restrict__ y_true,
                    const float* __restrict__ y_pred,
                    float* __restrict__ out) {
    __shared__ __align__(16) float rows[F_NBUF][F_CHUNK][CTC_V];
    const int b = blockIdx.x;
    const int tid = threadIdx.x;
    const int wave = tid >> 6;
    const int lane = tid & 63;
    const float* __restrict__ yb = y_pred + (size_t)b * CTC_T * CTC_V;

    if (wave != 0) {
        const int w = wave - 1;
#define FISSUE(c_) do {                                                    \
            const int t0_ = (c_) * F_CHUNK;                                \
            float* bufb_ = &rows[(c_) & (F_NBUF - 1)][0][0];               \
            for (int l_ = w; l_ < F_CHUNK; l_ += 3) {                      \
                const float* g_ = yb + (size_t)(t0_ + l_) * CTC_V + lane * 4; \
                float* d_ = bufb_ + l_ * CTC_V;                            \
                gld_lds16f(g_, d_);                                        \
                gld_lds16f(g_ + 256, d_ + 256);                            \
            }                                                              \
        } while (0)
        FISSUE(0); FISSUE(1); FISSUE(2);
        if (w == 0) asm volatile("s_waitcnt vmcnt(24)" ::: "memory");
        else        asm volatile("s_waitcnt vmcnt(20)" ::: "memory");
        __builtin_amdgcn_s_barrier();
        __builtin_amdgcn_sched_barrier(0);
        for (int c = 0; c < F_NCH; ++c) {
            if (c + 3 < F_NCH) FISSUE(c + 3);
            if (c <= F_NCH - 4) {
                if (w == 0) asm volatile("s_waitcnt vmcnt(24)" ::: "memory");
                else        asm volatile("s_waitcnt vmcnt(20)" ::: "memory");
            } else if (c == F_NCH - 3) {
                if (w == 0) asm volatile("s_waitcnt vmcnt(12)" ::: "memory");
                else        asm volatile("s_waitcnt vmcnt(10)" ::: "memory");
            } else if (c == F_NCH - 2) {
                asm volatile("s_waitcnt vmcnt(0)" ::: "memory");
            }
            __builtin_amdgcn_s_barrier();
            __builtin_amdgcn_sched_barrier(0);
        }
        return;
#undef FISSUE
    }

    const int labA = y_true[b * CTC_L + 2 * lane];
    const int labB = y_true[b * CTC_L + 2 * lane + 1];
    const int labPrev = __shfl_up(labB, 1);
    const float msk1 = (labA != labPrev) ? 1.0f : 0.0f;
    const float msk3 = (labB != labA) ? 1.0f : 0.0f;

    float a0 = 0.0f, a1 = 0.0f, a2 = 0.0f, a3 = 0.0f, a4 = 0.0f;
    float curScale = 1.0f;
    int curE = 0, Eacc = 0;
    float pAA0, pBA0, blA0, pAA1, pBA1, blA1, pAA2, pBA2, blA2, pAA3, pBA3, blA3;
    float pAB0, pBB0, blB0, pAB1, pBB1, blB1, pAB2, pBB2, blB2, pAB3, pBB3, blB3;
    float pAC0, pBC0, blC0, pAC1, pBC1, blC1, pAC2, pBC2, blC2, pAC3, pBC3, blC3;

#define FLOADG(S, l_) do {                                                 \
        const float* r0_ = bufc + ((l_) + 0) * CTC_V;                      \
        const float* r1_ = bufc + ((l_) + 1) * CTC_V;                      \
        const float* r2_ = bufc + ((l_) + 2) * CTC_V;                      \
        const float* r3_ = bufc + ((l_) + 3) * CTC_V;                      \
        pA##S##0 = r0_[labA]; pB##S##0 = r0_[labB]; bl##S##0 = r0_[BLANK]; \
        pA##S##1 = r1_[labA]; pB##S##1 = r1_[labB]; bl##S##1 = r1_[BLANK]; \
        pA##S##2 = r2_[labA]; pB##S##2 = r2_[labB]; bl##S##2 = r2_[BLANK]; \
        pA##S##3 = r3_[labA]; pB##S##3 = r3_[labB]; bl##S##3 = r3_[BLANK]; \
    } while (0)
#define FDOSTEP(S, k) do {                                                 \
        const float pb_ = bl##S##k + EPSF;                                 \
        const float pA_ = pA##S##k + EPSF;                                 \
        const float pB_ = pB##S##k + EPSF;                                 \
        const float pm1_ = dpp_mov0<0x138>(a3);                            \
        const float n0_ = (a0 + pm1_) * pb_;                               \
        const float n1_ = fmaf(msk1, pm1_, a0 + a1) * pA_;                 \
        const float n2_ = (a1 + a2) * pb_;                                 \
        const float n3_ = fmaf(msk3, a1, a2 + a3) * pB_;                   \
        const float n4_ = (a3 + a4) * pb_;                                 \
        a0 = n0_; a1 = n1_; a2 = n2_; a3 = n3_; a4 = n4_;                  \
    } while (0)
#define FDORN() do {                                                       \
        a0 *= curScale; a1 *= curScale; a2 *= curScale;                    \
        a3 *= curScale; a4 *= curScale;                                    \
        Eacc += curE;                                                      \
        float m_ = fmaxf(fmaxf(fmaxf(a0, a1), fmaxf(a2, a3)), a4);         \
        m_ = dpp_max<0x111>(m_); m_ = dpp_max<0x112>(m_);                  \
        m_ = dpp_max<0x114>(m_); m_ = dpp_max<0x118>(m_);                  \
        m_ = dpp_max<0x142>(m_); m_ = dpp_max<0x143>(m_);                  \
        const int mb_ = __builtin_amdgcn_readlane(__float_as_int(m_), 63); \
        const int e_ = (mb_ >> 23) & 255;                                  \
        int k_ = 127 + BIASE + 127 - e_;                                   \
        k_ = k_ > 254 ? 254 : (k_ < 1 ? 1 : k_);                           \
        curScale = __int_as_float((unsigned)k_ << 23);                     \
        curE = 127 - k_;                                                   \
    } while (0)
#define FPROC4_RN(S) do {                                                  \
        FDOSTEP(S, 0); FDORN();                                            \
        FDOSTEP(S, 1); FDOSTEP(S, 2); FDOSTEP(S, 3);                       \
    } while (0)

    __builtin_amdgcn_s_barrier();
    __builtin_amdgcn_sched_barrier(0);
    for (int c = 0; c < F_NCH; ++c) {
        const float* bufc = &rows[c & (F_NBUF - 1)][0][0];
        if (c == 0) {
            const float pb0 = bufc[BLANK] + EPSF;
            const float plA = bufc[labA] + EPSF;
            FLOADG(A, 0); FLOADG(B, 4); FLOADG(C, 8);
            a0 = (lane == 0) ? pb0 : 0.0f;
            a1 = (lane == 0) ? plA : 0.0f;
            FDOSTEP(A, 1); FDOSTEP(A, 2); FDOSTEP(A, 3);
            FLOADG(A, 12);
            FPROC4_RN(B); FPROC4_RN(C); FPROC4_RN(A);
        } else {
            FLOADG(A, 0); FLOADG(B, 4); FLOADG(C, 8);
            FPROC4_RN(A); FLOADG(A, 12);
            FPROC4_RN(B); FPROC4_RN(C); FPROC4_RN(A);
        }
        __builtin_amdgcn_s_barrier();
        __builtin_amdgcn_sched_barrier(0);
    }
    if (lane == 63) {
        out[b] = -(logf(a3 + a4) + (float)Eacc * LN2F);
    }
#undef FPROC4_RN
#undef FDORN
#undef FDOSTEP
#undef FLOADG
}

extern "C" void kernel_launch(void* const* d_in, const int* in_sizes, int n_in,
                              void* d_out, int out_size, void* d_ws, size_t ws_size,
                              hipStream_t stream) {
    (void)in_sizes; (void)n_in; (void)out_size;
    const int* y_true = (const int*)d_in[0];     // [B, L] int32
    const float* y_pred = (const float*)d_in[1]; // [B, T, V] float32
    float* out = (float*)d_out;                  // [B, 1] float32

    const size_t need = (size_t)CTC_B * CTC_T * ROWW * sizeof(uint32_t); // 17.8 MB
    if (ws_size >= need) {
        uint32_t* cmp = (uint32_t*)d_ws;
        ctc_gather<<<CTC_B * (CTC_T / K1ROWS), 256, 0, stream>>>(y_true, y_pred, cmp);
        ctc_scan<<<CTC_B, 128, 0, stream>>>(y_true, cmp, out);
    } else {
        ctc_fwd_stream<<<CTC_B, 256, 0, stream>>>(y_true, y_pred, out);
    }
}